// Round 5
// baseline (37.151 us; speedup 1.0000x reference)
//
#include <hip/hip_runtime.h>

typedef float f32x4 __attribute__((ext_vector_type(4)));

// QIL quantize one weight element.
// ref: p = max(p,0); s = 127/(c-p)
//      wq = |w|<p ? 0 : round(clip((|w|-p)*s*sign(w), -127, 127))
//      out = (|wq|/s + p) * sign(wq)   // sign of wq: rounded-to-0 -> exactly 0
__device__ __forceinline__ float qil1(float w, float p, float s, float inv_s) {
    float aw = fabsf(w);
    float q = rintf(fminf((aw - p) * s, 127.0f));   // half-even round == jnp.round
    float mag = fmaf(q, inv_s, p);                  // q/s + p (~1ulp vs IEEE div)
    return (aw < p || q == 0.0f) ? 0.0f : copysignf(mag, w);
}

__device__ __forceinline__ f32x4 qil4(f32x4 v, float p, float s, float inv_s) {
    f32x4 r;
    r.x = qil1(v.x, p, s, inv_s);
    r.y = qil1(v.y, p, s, inv_s);
    r.z = qil1(v.z, p, s, inv_s);
    r.w = qil1(v.w, p, s, inv_s);
    return r;
}

// One wave per 2 tokens: 2 idx loads -> 6 independent 16B row loads -> 6 nt
// stores. dim = 768 floats = 192 f32x4 = 3*64.
__global__ void __launch_bounds__(256)
qil_embed_kernel(const int* __restrict__ x,
                 const float* __restrict__ weight,
                 const float* __restrict__ pp,
                 const float* __restrict__ cp,
                 float* __restrict__ out,
                 int n_tokens, int dim4) {
    const float p     = fmaxf(pp[0], 0.0f);
    const float s     = 127.0f / (cp[0] - p);
    const float inv_s = 1.0f / s;

    const int wid  = threadIdx.x >> 6;
    const int lane = threadIdx.x & 63;
    const int tok0 = blockIdx.x * 8 + wid * 2;   // 2 tokens per wave
    if (tok0 >= n_tokens) return;

    const int row0 = __builtin_amdgcn_readfirstlane(x[tok0]);
    const int row1 = __builtin_amdgcn_readfirstlane(x[tok0 + 1]);

    const f32x4* __restrict__ src0 = (const f32x4*)weight + row0 * dim4;
    const f32x4* __restrict__ src1 = (const f32x4*)weight + row1 * dim4;
    f32x4* __restrict__ dst = (f32x4*)out + tok0 * dim4;

    f32x4 a0 = src0[lane];
    f32x4 a1 = src0[lane + 64];
    f32x4 a2 = src0[lane + 128];
    f32x4 b0 = src1[lane];
    f32x4 b1 = src1[lane + 64];
    f32x4 b2 = src1[lane + 128];

    __builtin_nontemporal_store(qil4(a0, p, s, inv_s), dst + lane);
    __builtin_nontemporal_store(qil4(a1, p, s, inv_s), dst + lane + 64);
    __builtin_nontemporal_store(qil4(a2, p, s, inv_s), dst + lane + 128);
    __builtin_nontemporal_store(qil4(b0, p, s, inv_s), dst + lane + 192);
    __builtin_nontemporal_store(qil4(b1, p, s, inv_s), dst + lane + 256);
    __builtin_nontemporal_store(qil4(b2, p, s, inv_s), dst + lane + 320);

    if (tok0 == 0 && lane == 0) {
        const long long total = (long long)n_tokens * dim4 * 4;
        out[total]     = s;
        out[total + 1] = p;
    }
}

extern "C" void kernel_launch(void* const* d_in, const int* in_sizes, int n_in,
                              void* d_out, int out_size, void* d_ws, size_t ws_size,
                              hipStream_t stream) {
    const int*   x  = (const int*)d_in[0];
    const float* w  = (const float*)d_in[1];
    const float* pp = (const float*)d_in[2];
    const float* cp = (const float*)d_in[3];
    float* out = (float*)d_out;

    const int n_tokens = in_sizes[0];            // 16384
    const int dim  = (out_size - 2) / n_tokens;  // 768
    const int dim4 = dim / 4;                    // 192

    const int blocks = (n_tokens + 7) / 8;       // 2048

    // DIAGNOSTIC: two identical, idempotent dispatches. dur_us - baseline(20.4)
    // measures one L3-warm full pass free of graph-launch overhead.
    qil_embed_kernel<<<dim3(blocks), dim3(256), 0, stream>>>(
        x, w, pp, cp, out, n_tokens, dim4);
    qil_embed_kernel<<<dim3(blocks), dim3(256), 0, stream>>>(
        x, w, pp, cp, out, n_tokens, dim4);
}

// Round 6
// 20.741 us; speedup vs baseline: 1.7912x; 1.7912x over previous
//
#include <hip/hip_runtime.h>

typedef float f32x4 __attribute__((ext_vector_type(4)));

// QIL quantize one weight element.
// ref: p = max(p,0); s = 127/(c-p)
//      wq = |w|<p ? 0 : round(clip((|w|-p)*s*sign(w), -127, 127))
//      out = (|wq|/s + p) * sign(wq)   // sign of wq: rounded-to-0 -> exactly 0
__device__ __forceinline__ float qil1(float w, float p, float s, float inv_s) {
    float aw = fabsf(w);
    float q = rintf(fminf((aw - p) * s, 127.0f));   // half-even round == jnp.round
    float mag = fmaf(q, inv_s, p);                  // q/s + p (~1ulp vs IEEE div)
    return (aw < p || q == 0.0f) ? 0.0f : copysignf(mag, w);
}

__device__ __forceinline__ f32x4 qil4(f32x4 v, float p, float s, float inv_s) {
    f32x4 r;
    r.x = qil1(v.x, p, s, inv_s);
    r.y = qil1(v.y, p, s, inv_s);
    r.z = qil1(v.z, p, s, inv_s);
    r.w = qil1(v.w, p, s, inv_s);
    return r;
}

// One wave per 2 tokens: 2 idx loads -> 6 independent 16B row loads -> 6 nt
// stores. dim = 768 floats = 192 f32x4 = 3*64.
// Measured: device time ~16.7 us (= ~5.9 TB/s combined, 93% of the 6.29 TB/s
// copy ceiling; harness fills evict L3 between replays so reads are HBM-cold).
// Store policy / loads-in-flight / VALU cost all proven flat (R1-R4).
__global__ void __launch_bounds__(256)
qil_embed_kernel(const int* __restrict__ x,
                 const float* __restrict__ weight,
                 const float* __restrict__ pp,
                 const float* __restrict__ cp,
                 float* __restrict__ out,
                 int n_tokens, int dim4) {
    const float p     = fmaxf(pp[0], 0.0f);
    const float s     = 127.0f / (cp[0] - p);
    const float inv_s = 1.0f / s;

    const int wid  = threadIdx.x >> 6;
    const int lane = threadIdx.x & 63;
    const int tok0 = blockIdx.x * 8 + wid * 2;   // 2 tokens per wave
    if (tok0 >= n_tokens) return;

    const int row0 = __builtin_amdgcn_readfirstlane(x[tok0]);
    const int row1 = __builtin_amdgcn_readfirstlane(x[tok0 + 1]);

    const f32x4* __restrict__ src0 = (const f32x4*)weight + row0 * dim4;
    const f32x4* __restrict__ src1 = (const f32x4*)weight + row1 * dim4;
    f32x4* __restrict__ dst = (f32x4*)out + tok0 * dim4;

    f32x4 a0 = src0[lane];
    f32x4 a1 = src0[lane + 64];
    f32x4 a2 = src0[lane + 128];
    f32x4 b0 = src1[lane];
    f32x4 b1 = src1[lane + 64];
    f32x4 b2 = src1[lane + 128];

    __builtin_nontemporal_store(qil4(a0, p, s, inv_s), dst + lane);
    __builtin_nontemporal_store(qil4(a1, p, s, inv_s), dst + lane + 64);
    __builtin_nontemporal_store(qil4(a2, p, s, inv_s), dst + lane + 128);
    __builtin_nontemporal_store(qil4(b0, p, s, inv_s), dst + lane + 192);
    __builtin_nontemporal_store(qil4(b1, p, s, inv_s), dst + lane + 256);
    __builtin_nontemporal_store(qil4(b2, p, s, inv_s), dst + lane + 320);

    // tuple outputs 1 and 2: weight_scaling_factor, pruning point
    if (tok0 == 0 && lane == 0) {
        const long long total = (long long)n_tokens * dim4 * 4;
        out[total]     = s;
        out[total + 1] = p;
    }
}

extern "C" void kernel_launch(void* const* d_in, const int* in_sizes, int n_in,
                              void* d_out, int out_size, void* d_ws, size_t ws_size,
                              hipStream_t stream) {
    const int*   x  = (const int*)d_in[0];
    const float* w  = (const float*)d_in[1];
    const float* pp = (const float*)d_in[2];
    const float* cp = (const float*)d_in[3];
    float* out = (float*)d_out;

    const int n_tokens = in_sizes[0];            // 16384
    const int dim  = (out_size - 2) / n_tokens;  // 768
    const int dim4 = dim / 4;                    // 192

    const int blocks = (n_tokens + 7) / 8;       // 2048: 4 waves x 2 tokens
    qil_embed_kernel<<<dim3(blocks), dim3(256), 0, stream>>>(
        x, w, pp, cp, out, n_tokens, dim4);
}